// Round 14
// baseline (1004.346 us; speedup 1.0000x reference)
//
#include <hip/hip_runtime.h>
#include <hip/hip_cooperative_groups.h>

namespace cg = cooperative_groups;

// ---------------------------------------------------------------------------
// 3-layer GCN (DGL GraphConv, norm='both') on N=100k nodes, E=800k edges.
// Round 14: r13 cooperative single-kernel, fixed:
//  - grid sized from hipOccupancyMaxActiveBlocksPerMultiprocessor (r13's
//    hard-coded 1024 blocks exceeded co-residency -> silent launch failure)
//  - launch return code checked; on failure fall back to the proven 8-dispatch
//    path using the SAME phase device functions (r12-equivalent).
// Phases: {zero+packW} -> fill(NT) -> gemm0 -> gather0 -> gemm1 -> gather1
//         -> gemm2 -> gather2.
// ---------------------------------------------------------------------------

typedef short s16x8 __attribute__((ext_vector_type(8)));
typedef float f32x4 __attribute__((ext_vector_type(4)));

static constexpr int CAP = 24;   // bucket slots per node (P(deg>24)~1e-6)

__device__ __forceinline__ unsigned short f2bf(float f) {
    unsigned int u = __float_as_uint(f);
    u += 0x7FFFu + ((u >> 16) & 1u);   // round-to-nearest-even
    return (unsigned short)(u >> 16);
}
__device__ __forceinline__ float bf2f(unsigned short v) {
    return __uint_as_float((unsigned int)v << 16);
}

struct GcnP {
    const int*   src;
    const int*   dst;
    const float* w;
    const float* x;
    const float* W0; const float* b0;
    const float* W1; const float* b1;
    const float* W2; const float* b2;
    unsigned short* Wp;      // Wp0 | +16384 Wp1 | +32768 Wp2 (elements)
    unsigned short* xh;      // hidden state, [N][128] bf16
    unsigned short* y;       // gemm output,  [N][128] bf16 (PC=64 uses prefix)
    float4* swb;             // bucket records [N][CAP]
    int2*   spill;
    int*    dego;
    int*    cursor;          // becomes in-degree
    int*    spill_cnt;
    float*  out;
    int N, E;
};

// ---- P0: zero counters + pack weights into MFMA fragment order ----
// Fragment mapping (same for A and B, cancels HW k-order):
//   k = kk*32 + (lane>>4)*8 + j ; col = ct*16 + (lane&15)
__device__ __forceinline__ void phase_init(const GcnP& p, int gtid, int gsz) {
    for (int i = gtid; i < 2 * p.N + 4; i += gsz) p.dego[i] = 0;
    for (int idx = gtid; idx < 40960; idx += gsz) {
        if (idx < 32768) {                   // W0 / W1, PC=128
            const float* W = (idx < 16384) ? p.W0 : p.W1;
            unsigned short* D = p.Wp + ((idx < 16384) ? 0 : 16384);
            int i = idx & 16383;
            int k = i >> 7, col = i & 127;
            float v = W[k * 128 + col];
            int kk = k >> 5, kr = k & 31;
            int ln = ((kr >> 3) << 4) | (col & 15);
            int ct = col >> 4, j = kr & 7;
            D[(((kk * 8) + ct) * 64 + ln) * 8 + j] = f2bf(v);
        } else {                             // W2, PC=64, dact=47
            int i = idx - 32768;
            int k = i >> 6, col = i & 63;
            float v = (col < 47) ? p.W2[k * 47 + col] : 0.0f;
            int kk = k >> 5, kr = k & 31;
            int ln = ((kr >> 3) << 4) | (col & 15);
            int ct = col >> 4, j = kr & 7;
            (p.Wp + 32768)[(((kk * 4) + ct) * 64 + ln) * 8 + j] = f2bf(v);
        }
    }
}

// ---- P1: bucket fill (NT record stores; L2 stays coherent, NT only skips
//      allocation). cursor's final value = in-degree. ----
__device__ __forceinline__ void phase_fill(const GcnP& p, int gtid, int gsz) {
    for (int e = gtid; e < p.E; e += gsz) {
        int s = p.src[e];
        int d = p.dst[e];
        atomicAdd(&p.dego[s], 1);
        int pos = atomicAdd(&p.cursor[d], 1);
        if (pos < CAP) {
            f32x4 r = { __int_as_float(s), p.w[e], p.w[p.E + e],
                        p.w[2 * (size_t)p.E + e] };
            __builtin_nontemporal_store(r, (f32x4*)&p.swb[(size_t)d * CAP + pos]);
        } else {
            int sp = atomicAdd(p.spill_cnt, 1);
            p.spill[sp] = make_int2(d, e);
        }
    }
}

// ---- 64-row MFMA gemm tile (LDS-free). C/D: col=ct*16+(lane&15),
//      row = r0 + (lane>>4)*4 + i. ----
template<int PC, bool F32IN>
__device__ __forceinline__ void gemm_tile(int row0, const void* hvoid,
        const unsigned short* Wp, unsigned short* y, int N, int lane, int wid) {
    constexpr int CT = PC / 16;
    const int r0   = row0 + wid * 16;
    const int kgrp = lane >> 4;
    const int c    = lane & 15;
    int ar = r0 + c;
    if (ar > N - 1) ar = N - 1;

    f32x4 acc[CT];
    #pragma unroll
    for (int ct = 0; ct < CT; ++ct) acc[ct] = {0.f, 0.f, 0.f, 0.f};

    #pragma unroll
    for (int kk = 0; kk < 4; ++kk) {
        s16x8 af;
        if (F32IN) {
            const float* xrow = (const float*)hvoid + (size_t)ar * 128;
            float4 u0 = *(const float4*)&xrow[kk * 32 + kgrp * 8];
            float4 u1 = *(const float4*)&xrow[kk * 32 + kgrp * 8 + 4];
            af[0] = (short)f2bf(u0.x); af[1] = (short)f2bf(u0.y);
            af[2] = (short)f2bf(u0.z); af[3] = (short)f2bf(u0.w);
            af[4] = (short)f2bf(u1.x); af[5] = (short)f2bf(u1.y);
            af[6] = (short)f2bf(u1.z); af[7] = (short)f2bf(u1.w);
        } else {
            const unsigned short* hrow =
                (const unsigned short*)hvoid + (size_t)ar * 128 + kgrp * 8;
            af = *(const s16x8*)&hrow[kk * 32];
        }
        #pragma unroll
        for (int ct = 0; ct < CT; ++ct) {
            s16x8 bf = *(const s16x8*)&Wp[((size_t)(kk * CT + ct) * 64 + lane) * 8];
            acc[ct] = __builtin_amdgcn_mfma_f32_16x16x32_bf16(af, bf, acc[ct], 0, 0, 0);
        }
    }
    #pragma unroll
    for (int ct = 0; ct < CT; ++ct) {
        #pragma unroll
        for (int i = 0; i < 4; ++i) {
            int row = r0 + kgrp * 4 + i;
            if (row < N) y[(size_t)row * PC + ct * 16 + c] = f2bf(acc[ct][i]);
        }
    }
}

template<int PC, bool F32IN>
__device__ __forceinline__ void phase_gemm(const GcnP& p, const void* h,
        const unsigned short* Wp, int bid, int nb, int lane, int wid) {
    const int tiles = (p.N + 63) >> 6;
    for (int tb = bid; tb < tiles; tb += nb)
        gemm_tile<PC, F32IN>(tb * 64, h, Wp, p.y, p.N, lane, wid);
}

// ---- wave-per-node gather + fused finalize (r9 form) ----
template<int PC, int WSEL, bool FINAL>
__device__ __forceinline__ void gather_node(const GcnP& p,
        const unsigned short* yb, const float* bvec, void* outp, int n, int t) {
    constexpr int TPN = PC / 4;
    constexpr int EPG = 64 / TPN;
    const int lane = t & (TPN - 1);
    const int g    = t / TPN;

    const ushort4* yv = (const ushort4*)yb;
    const float4* rec = p.swb + (size_t)n * CAP;
    const int dg  = p.cursor[n];
    const int cnt = dg < CAP ? dg : CAP;

    float a0 = 0.f, a1 = 0.f, a2 = 0.f, a3 = 0.f;
    int q = g;

#define SELW(m) ((WSEL == 0) ? (m).y : (WSEL == 1) ? (m).z : (m).w)
#define EDGE_FMA(m, v) do {                                                   \
        int _s = __float_as_int((m).x);                                       \
        int _d = p.dego[_s]; if (_d < 1) _d = 1;                              \
        float _w = SELW(m) * rsqrtf((float)_d);                               \
        a0 = fmaf(bf2f((v).x), _w, a0);                                       \
        a1 = fmaf(bf2f((v).y), _w, a1);                                       \
        a2 = fmaf(bf2f((v).z), _w, a2);                                       \
        a3 = fmaf(bf2f((v).w), _w, a3);                                       \
    } while (0)

    for (; q + 3 * EPG < cnt; q += 4 * EPG) {
        float4 m0 = rec[q];
        float4 m1 = rec[q + EPG];
        float4 m2 = rec[q + 2 * EPG];
        float4 m3 = rec[q + 3 * EPG];
        ushort4 v0 = yv[(size_t)__float_as_int(m0.x) * TPN + lane];
        ushort4 v1 = yv[(size_t)__float_as_int(m1.x) * TPN + lane];
        ushort4 v2 = yv[(size_t)__float_as_int(m2.x) * TPN + lane];
        ushort4 v3 = yv[(size_t)__float_as_int(m3.x) * TPN + lane];
        EDGE_FMA(m0, v0); EDGE_FMA(m1, v1); EDGE_FMA(m2, v2); EDGE_FMA(m3, v3);
    }
    for (; q + EPG < cnt; q += 2 * EPG) {
        float4 m0 = rec[q];
        float4 m1 = rec[q + EPG];
        ushort4 v0 = yv[(size_t)__float_as_int(m0.x) * TPN + lane];
        ushort4 v1 = yv[(size_t)__float_as_int(m1.x) * TPN + lane];
        EDGE_FMA(m0, v0); EDGE_FMA(m1, v1);
    }
    if (q < cnt) {
        float4 m0 = rec[q];
        ushort4 v0 = yv[(size_t)__float_as_int(m0.x) * TPN + lane];
        EDGE_FMA(m0, v0);
    }
    if (dg > CAP && g == 0) {            // exact-overflow path (empty in practice)
        const float* wl = p.w + (size_t)WSEL * p.E;
        int sc = *p.spill_cnt;
        for (int i = 0; i < sc; ++i) {
            int2 sp = p.spill[i];
            if (sp.x == n) {
                int e = sp.y;
                int s0 = p.src[e];
                int d0 = p.dego[s0]; if (d0 < 1) d0 = 1;
                float w0 = wl[e] * rsqrtf((float)d0);
                ushort4 v0 = yv[(size_t)s0 * TPN + lane];
                a0 = fmaf(bf2f(v0.x), w0, a0);
                a1 = fmaf(bf2f(v0.y), w0, a1);
                a2 = fmaf(bf2f(v0.z), w0, a2);
                a3 = fmaf(bf2f(v0.w), w0, a3);
            }
        }
    }
#undef EDGE_FMA
#undef SELW

    #pragma unroll
    for (int m = TPN; m < 64; m <<= 1) {
        a0 += __shfl_xor(a0, m, 64);
        a1 += __shfl_xor(a1, m, 64);
        a2 += __shfl_xor(a2, m, 64);
        a3 += __shfl_xor(a3, m, 64);
    }
    if (g == 0) {
        const float inv = rsqrtf((float)(dg < 1 ? 1 : dg));
        if (FINAL) {
            float* out = (float*)outp;
            const int c = lane * 4;
            float aa[4] = {a0, a1, a2, a3};
            #pragma unroll
            for (int j = 0; j < 4; ++j) {
                if (c + j < 47) out[(size_t)n * 47 + c + j] = fmaf(aa[j], inv, bvec[c + j]);
            }
        } else {
            unsigned short* out = (unsigned short*)outp;
            float4 bb = *(const float4*)&bvec[lane * 4];
            float4 v;
            v.x = fmaxf(fmaf(a0, inv, bb.x), 0.f);
            v.y = fmaxf(fmaf(a1, inv, bb.y), 0.f);
            v.z = fmaxf(fmaf(a2, inv, bb.z), 0.f);
            v.w = fmaxf(fmaf(a3, inv, bb.w), 0.f);
            ushort4 o;
            o.x = f2bf(v.x); o.y = f2bf(v.y); o.z = f2bf(v.z); o.w = f2bf(v.w);
            *(ushort4*)&out[(size_t)n * PC + lane * 4] = o;
        }
    }
}

template<int PC, int WSEL, bool FINAL>
__device__ __forceinline__ void phase_gather(const GcnP& p, const float* bvec,
        void* outp, int gw, int nwv, int lane) {
    for (int n = gw; n < p.N; n += nwv)
        gather_node<PC, WSEL, FINAL>(p, p.y, bvec, outp, n, lane);
}

// ---------------------------------------------------------------------------
// Cooperative single-kernel path.
// ---------------------------------------------------------------------------
__global__ __launch_bounds__(256)
void gcn_all(GcnP p) {
    cg::grid_group grid = cg::this_grid();
    const int tid  = threadIdx.x;
    const int bid  = blockIdx.x;
    const int nb   = gridDim.x;
    const int gtid = bid * 256 + tid;
    const int gsz  = nb * 256;
    const int lane = tid & 63;
    const int wid  = tid >> 6;
    const int gw   = bid * 4 + wid;
    const int nwv  = nb * 4;

    phase_init(p, gtid, gsz);
    grid.sync();
    phase_fill(p, gtid, gsz);
    grid.sync();
    phase_gemm<128, true>(p, p.x, p.Wp, bid, nb, lane, wid);
    grid.sync();
    phase_gather<128, 0, false>(p, p.b0, p.xh, gw, nwv, lane);
    grid.sync();
    phase_gemm<128, false>(p, p.xh, p.Wp + 16384, bid, nb, lane, wid);
    grid.sync();
    phase_gather<128, 1, false>(p, p.b1, p.xh, gw, nwv, lane);
    grid.sync();
    phase_gemm<64, false>(p, p.xh, p.Wp + 32768, bid, nb, lane, wid);
    grid.sync();
    phase_gather<64, 2, true>(p, p.b2, p.out, gw, nwv, lane);
}

// ---------------------------------------------------------------------------
// Fallback multi-dispatch wrappers (same phase bodies, plain launches).
// ---------------------------------------------------------------------------
__global__ __launch_bounds__(256) void k_init(GcnP p) {
    phase_init(p, blockIdx.x * 256 + threadIdx.x, gridDim.x * 256);
}
__global__ __launch_bounds__(256) void k_fill(GcnP p) {
    phase_fill(p, blockIdx.x * 256 + threadIdx.x, gridDim.x * 256);
}
__global__ __launch_bounds__(256) void k_gemm0(GcnP p) {
    phase_gemm<128, true>(p, p.x, p.Wp, blockIdx.x, gridDim.x,
                          threadIdx.x & 63, threadIdx.x >> 6);
}
__global__ __launch_bounds__(256) void k_gemm1(GcnP p) {
    phase_gemm<128, false>(p, p.xh, p.Wp + 16384, blockIdx.x, gridDim.x,
                           threadIdx.x & 63, threadIdx.x >> 6);
}
__global__ __launch_bounds__(256) void k_gemm2(GcnP p) {
    phase_gemm<64, false>(p, p.xh, p.Wp + 32768, blockIdx.x, gridDim.x,
                          threadIdx.x & 63, threadIdx.x >> 6);
}
__global__ __launch_bounds__(256) void k_gather0(GcnP p) {
    phase_gather<128, 0, false>(p, p.b0, p.xh,
        blockIdx.x * 4 + (threadIdx.x >> 6), gridDim.x * 4, threadIdx.x & 63);
}
__global__ __launch_bounds__(256) void k_gather1(GcnP p) {
    phase_gather<128, 1, false>(p, p.b1, p.xh,
        blockIdx.x * 4 + (threadIdx.x >> 6), gridDim.x * 4, threadIdx.x & 63);
}
__global__ __launch_bounds__(256) void k_gather2(GcnP p) {
    phase_gather<64, 2, true>(p, p.b2, p.out,
        blockIdx.x * 4 + (threadIdx.x >> 6), gridDim.x * 4, threadIdx.x & 63);
}

extern "C" void kernel_launch(void* const* d_in, const int* in_sizes, int n_in,
                              void* d_out, int out_size, void* d_ws, size_t ws_size,
                              hipStream_t stream) {
    const int N = in_sizes[0] / 128;
    const int E = in_sizes[1];

    char* p = (char*)d_ws;
    unsigned short* xh = (unsigned short*)p; p += (size_t)N * 128 * sizeof(unsigned short);
    unsigned short* y  = (unsigned short*)p; p += (size_t)N * 128 * sizeof(unsigned short);
    float4* swb    = (float4*)p; p += (size_t)N * CAP * sizeof(float4);
    int2*   spill  = (int2*)p;   p += (size_t)E * sizeof(int2);
    unsigned short* Wp = (unsigned short*)p; p += (size_t)(16384 * 2 + 8192) * sizeof(unsigned short);
    int*    dego   = (int*)p;    p += (size_t)N * sizeof(int);
    int*    cursor = (int*)p;    p += (size_t)N * sizeof(int);
    int*    spill_cnt = (int*)p; p += 4 * sizeof(int);

    GcnP prm;
    prm.src = (const int*)d_in[1];
    prm.dst = (const int*)d_in[2];
    prm.w   = (const float*)d_in[3];
    prm.x   = (const float*)d_in[0];
    prm.W0  = (const float*)d_in[4];  prm.b0 = (const float*)d_in[5];
    prm.W1  = (const float*)d_in[6];  prm.b1 = (const float*)d_in[7];
    prm.W2  = (const float*)d_in[8];  prm.b2 = (const float*)d_in[9];
    prm.Wp  = Wp;
    prm.xh  = xh;
    prm.y   = y;
    prm.swb = swb;
    prm.spill = spill;
    prm.dego = dego;
    prm.cursor = cursor;
    prm.spill_cnt = spill_cnt;
    prm.out = (float*)d_out;
    prm.N = N;
    prm.E = E;

    // ---- size the cooperative grid from actual occupancy ----
    int dev = 0;
    (void)hipGetDevice(&dev);
    int numCU = 0;
    (void)hipDeviceGetAttribute(&numCU, hipDeviceAttributeMultiprocessorCount, dev);
    int maxPerCU = 0;
    hipError_t oe = hipOccupancyMaxActiveBlocksPerMultiprocessor(
        &maxPerCU, (const void*)gcn_all, 256, 0);

    bool done = false;
    if (oe == hipSuccess && numCU > 0 && maxPerCU > 0) {
        int grid = maxPerCU * numCU;
        if (grid > 1024) grid = 1024;
        if (grid >= 256) {
            void* args[] = { (void*)&prm };
            hipError_t le = hipLaunchCooperativeKernel(
                (void*)gcn_all, dim3(grid), dim3(256), args, 0, stream);
            done = (le == hipSuccess);
        }
    }

    if (!done) {   // proven multi-dispatch fallback (r12-equivalent)
        const int zblocks = (2 * N + 4 + 255) / 256;
        k_init<<<zblocks, 256, 0, stream>>>(prm);
        k_fill<<<(E + 255) / 256, 256, 0, stream>>>(prm);
        k_gemm0<<<(N + 63) / 64, 256, 0, stream>>>(prm);
        k_gather0<<<(N + 3) / 4, 256, 0, stream>>>(prm);
        k_gemm1<<<(N + 63) / 64, 256, 0, stream>>>(prm);
        k_gather1<<<(N + 3) / 4, 256, 0, stream>>>(prm);
        k_gemm2<<<(N + 63) / 64, 256, 0, stream>>>(prm);
        k_gather2<<<(N + 3) / 4, 256, 0, stream>>>(prm);
    }
}

// Round 15
// 264.691 us; speedup vs baseline: 3.7944x; 3.7944x over previous
//
#include <hip/hip_runtime.h>

// ---------------------------------------------------------------------------
// 3-layer GCN (DGL GraphConv, norm='both') on N=100k nodes, E=800k edges.
// Round 15 = r12 structure (best bracket: init_pack fusion + NT-store mega
// fill + wave-per-node gathers + LDS-free MFMA gemms), with the gathers
// widened to ushort8 lanes: TPN 32->16 (128-wide) / 16->8 (64-wide), EPG
// 2->4 / 4->8. Doubles independent edge chains in flight per wave, halves
// load instruction count. Persistent-cooperative r13/r14 abandoned (serial
// per-wave loops collapsed MLP: 1004us).
// Per layer: y = bf16(h @ W) ; h' = bf16(relu(sum_e y[s]*w*invo[s] *invi + b))
// ---------------------------------------------------------------------------

typedef short s16x8 __attribute__((ext_vector_type(8)));
typedef unsigned short u16x8 __attribute__((ext_vector_type(8)));
typedef float f32x4 __attribute__((ext_vector_type(4)));

static constexpr int CAP = 24;   // bucket slots per node (P(deg>24)~1e-6)

__device__ __forceinline__ unsigned short f2bf(float f) {
    unsigned int u = __float_as_uint(f);
    u += 0x7FFFu + ((u >> 16) & 1u);   // round-to-nearest-even
    return (unsigned short)(u >> 16);
}
__device__ __forceinline__ float bf2f(unsigned short v) {
    return __uint_as_float((unsigned int)v << 16);
}

// ---- init: pack all three weight matrices into MFMA fragment order AND
//      zero the counter arrays (dego, cursor, spill_cnt) in one dispatch ----
// Fragment mapping (same for A and B, cancels HW k-order):
//   k = kk*32 + (lane>>4)*8 + j ; col = ct*16 + (lane&15)
__global__ __launch_bounds__(256)
void init_pack(const float* __restrict__ W0, const float* __restrict__ W1,
               const float* __restrict__ W2, unsigned short* __restrict__ Wp,
               int* __restrict__ zbase, int nz) {
    int idx = blockIdx.x * 256 + threadIdx.x;
    if (idx < 32768) {                       // W0 / W1, PC=128, dact=128
        const float* W = (idx < 16384) ? W0 : W1;
        unsigned short* D = Wp + ((idx < 16384) ? 0 : 16384);
        int i = idx & 16383;
        int k = i >> 7, col = i & 127;
        float v = W[k * 128 + col];
        int kk = k >> 5, kr = k & 31;
        int lane = ((kr >> 3) << 4) | (col & 15);
        int ct = col >> 4, j = kr & 7;
        D[(((kk * 8) + ct) * 64 + lane) * 8 + j] = f2bf(v);
    } else if (idx < 40960) {                // W2, PC=64, dact=47
        int i = idx - 32768;
        int k = i >> 6, col = i & 63;
        float v = (col < 47) ? W2[k * 47 + col] : 0.0f;
        int kk = k >> 5, kr = k & 31;
        int lane = ((kr >> 3) << 4) | (col & 15);
        int ct = col >> 4, j = kr & 7;
        (Wp + 32768)[(((kk * 4) + ct) * 64 + lane) * 8 + j] = f2bf(v);
    }
    for (int i = idx; i < nz; i += gridDim.x * 256) zbase[i] = 0;
}

// ---------------------------------------------------------------------------
// Mega-kernel: graph build + layer-0 GEMM in one dispatch.
// blockIdx % 3 == 2 -> gemm0 block; else fill block (nt record stores).
// ---------------------------------------------------------------------------
__global__ __launch_bounds__(256)
void mega_fill_gemm0(const int* __restrict__ src, const int* __restrict__ dst,
                     const float* __restrict__ w, int E,
                     int* __restrict__ dego, int* __restrict__ cursor,
                     float4* __restrict__ swb,
                     int* __restrict__ spill_cnt, int2* __restrict__ spill,
                     const float* __restrict__ x,
                     const unsigned short* __restrict__ Wp0,
                     unsigned short* __restrict__ y, int N, int gemm_blocks) {
    const int b = blockIdx.x;
    if (b % 3 == 2) {
        // ---- gemm0: y[N][128] = bf16( bf16(x) @ Wp0 ) ----
        const int gb = b / 3;
        if (gb >= gemm_blocks) return;
        const int lane = threadIdx.x & 63;
        const int wid  = threadIdx.x >> 6;
        const int row0 = gb * 64 + wid * 16;
        const int kgrp = lane >> 4;
        const int c    = lane & 15;
        int ar = row0 + c;
        if (ar > N - 1) ar = N - 1;
        const float* xrow = &x[(size_t)ar * 128];

        f32x4 acc[8];
        #pragma unroll
        for (int ct = 0; ct < 8; ++ct) acc[ct] = {0.f, 0.f, 0.f, 0.f};

        #pragma unroll
        for (int kk = 0; kk < 4; ++kk) {
            float4 u0 = *(const float4*)&xrow[kk * 32 + kgrp * 8];
            float4 u1 = *(const float4*)&xrow[kk * 32 + kgrp * 8 + 4];
            s16x8 af;
            af[0] = (short)f2bf(u0.x); af[1] = (short)f2bf(u0.y);
            af[2] = (short)f2bf(u0.z); af[3] = (short)f2bf(u0.w);
            af[4] = (short)f2bf(u1.x); af[5] = (short)f2bf(u1.y);
            af[6] = (short)f2bf(u1.z); af[7] = (short)f2bf(u1.w);
            #pragma unroll
            for (int ct = 0; ct < 8; ++ct) {
                s16x8 bf = *(const s16x8*)&Wp0[((size_t)(kk * 8 + ct) * 64 + lane) * 8];
                acc[ct] = __builtin_amdgcn_mfma_f32_16x16x32_bf16(af, bf, acc[ct], 0, 0, 0);
            }
        }
        #pragma unroll
        for (int ct = 0; ct < 8; ++ct) {
            #pragma unroll
            for (int i = 0; i < 4; ++i) {
                int row = row0 + kgrp * 4 + i;
                if (row < N) y[(size_t)row * 128 + ct * 16 + c] = f2bf(acc[ct][i]);
            }
        }
    } else {
        // ---- fill: one edge per thread; nt store for the 16B record ----
        const int fb = b - b / 3;
        int e = fb * 256 + (int)threadIdx.x;
        if (e >= E) return;
        int s = src[e];
        int d = dst[e];
        atomicAdd(&dego[s], 1);
        int pos = atomicAdd(&cursor[d], 1);
        if (pos < CAP) {
            f32x4 r = { __int_as_float(s), w[e], w[E + e], w[2 * (size_t)E + e] };
            __builtin_nontemporal_store(r, (f32x4*)&swb[(size_t)d * CAP + pos]);
        } else {
            int sp = atomicAdd(spill_cnt, 1);
            spill[sp] = make_int2(d, e);
        }
    }
}

// ---------------------------------------------------------------------------
// LDS-free MFMA GEMM (layers 1,2): y[N][PC](bf16) = bf16( h[N][128](bf16) @ Wp )
// C/D layout: col = ct*16 + (lane&15), row = (lane>>4)*4 + i.
// ---------------------------------------------------------------------------
template<int PC>
__global__ __launch_bounds__(256)
void gemm_direct(const unsigned short* __restrict__ h,
                 const unsigned short* __restrict__ Wp,
                 unsigned short* __restrict__ y, int N) {
    constexpr int CT = PC / 16;
    const int lane = threadIdx.x & 63;
    const int wid  = threadIdx.x >> 6;
    const int row0 = blockIdx.x * 64 + wid * 16;
    const int kgrp = lane >> 4;
    const int c    = lane & 15;

    int ar = row0 + c;
    if (ar > N - 1) ar = N - 1;
    const unsigned short* hrow = &h[(size_t)ar * 128 + kgrp * 8];

    f32x4 acc[CT];
    #pragma unroll
    for (int ct = 0; ct < CT; ++ct) acc[ct] = {0.f, 0.f, 0.f, 0.f};

    #pragma unroll
    for (int kk = 0; kk < 4; ++kk) {
        s16x8 af = *(const s16x8*)&hrow[kk * 32];
        #pragma unroll
        for (int ct = 0; ct < CT; ++ct) {
            s16x8 bf = *(const s16x8*)&Wp[((size_t)(kk * CT + ct) * 64 + lane) * 8];
            acc[ct] = __builtin_amdgcn_mfma_f32_16x16x32_bf16(af, bf, acc[ct], 0, 0, 0);
        }
    }

    #pragma unroll
    for (int ct = 0; ct < CT; ++ct) {
        #pragma unroll
        for (int i = 0; i < 4; ++i) {
            int row = row0 + kgrp * 4 + i;
            if (row < N) y[(size_t)row * PC + ct * 16 + c] = f2bf(acc[ct][i]);
        }
    }
}

// ---------------------------------------------------------------------------
// Wave-per-node gather + fused finalize, ushort8 lanes.
// TPN = PC/8 lanes cover one row (16B load each); EPG = 64/TPN edge groups
// on interleaved slots (4 or 8 chains in flight); shfl_xor combine.
// edge weight = w * rsqrt(max(outdeg[src],1)); invi = rsqrt(max(indeg,1)).
// ---------------------------------------------------------------------------
template<int PC, int WSEL, bool FINAL>
__global__ __launch_bounds__(256)
void gather_w(const unsigned short* __restrict__ yb, const float4* __restrict__ swb,
              const int* __restrict__ degi, const int* __restrict__ dego,
              const int* __restrict__ spill_cnt, const int2* __restrict__ spill,
              const int* __restrict__ src, const float* __restrict__ wl,
              const float* __restrict__ b, void* __restrict__ outp, int N) {
    constexpr int TPN = PC / 8;        // lanes per row (16 or 8)
    constexpr int EPG = 64 / TPN;      // edge groups per node (4 or 8)
    const int n = blockIdx.x * 4 + (threadIdx.x >> 6);
    if (n >= N) return;
    const int t    = threadIdx.x & 63;
    const int lane = t & (TPN - 1);
    const int g    = t / TPN;

    const u16x8* yv = (const u16x8*)yb;      // TPN u16x8 per row
    const float4* rec = swb + (size_t)n * CAP;
    const int dg  = degi[n];
    const int cnt = dg < CAP ? dg : CAP;

    float a[8];
    #pragma unroll
    for (int j = 0; j < 8; ++j) a[j] = 0.f;
    int p = g;

#define SELW(m) ((WSEL == 0) ? (m).y : (WSEL == 1) ? (m).z : (m).w)
#define EDGE_FMA(m, v) do {                                                   \
        int _s = __float_as_int((m).x);                                       \
        int _d = dego[_s]; if (_d < 1) _d = 1;                                \
        float _w = SELW(m) * rsqrtf((float)_d);                               \
        _Pragma("unroll")                                                     \
        for (int _j = 0; _j < 8; ++_j)                                        \
            a[_j] = fmaf(bf2f((unsigned short)(v)[_j]), _w, a[_j]);           \
    } while (0)

    for (; p + 3 * EPG < cnt; p += 4 * EPG) {
        float4 m0 = rec[p];
        float4 m1 = rec[p + EPG];
        float4 m2 = rec[p + 2 * EPG];
        float4 m3 = rec[p + 3 * EPG];
        u16x8 v0 = yv[(size_t)__float_as_int(m0.x) * TPN + lane];
        u16x8 v1 = yv[(size_t)__float_as_int(m1.x) * TPN + lane];
        u16x8 v2 = yv[(size_t)__float_as_int(m2.x) * TPN + lane];
        u16x8 v3 = yv[(size_t)__float_as_int(m3.x) * TPN + lane];
        EDGE_FMA(m0, v0); EDGE_FMA(m1, v1); EDGE_FMA(m2, v2); EDGE_FMA(m3, v3);
    }
    for (; p + EPG < cnt; p += 2 * EPG) {
        float4 m0 = rec[p];
        float4 m1 = rec[p + EPG];
        u16x8 v0 = yv[(size_t)__float_as_int(m0.x) * TPN + lane];
        u16x8 v1 = yv[(size_t)__float_as_int(m1.x) * TPN + lane];
        EDGE_FMA(m0, v0); EDGE_FMA(m1, v1);
    }
    if (p < cnt) {
        float4 m0 = rec[p];
        u16x8 v0 = yv[(size_t)__float_as_int(m0.x) * TPN + lane];
        EDGE_FMA(m0, v0);
    }
    if (dg > CAP && g == 0) {            // exact-overflow path (empty in practice)
        int sc = *spill_cnt;
        for (int i = 0; i < sc; ++i) {
            int2 sp = spill[i];
            if (sp.x == n) {
                int e = sp.y;
                int s0 = src[e];
                int d0 = dego[s0]; if (d0 < 1) d0 = 1;
                float w0 = wl[e] * rsqrtf((float)d0);
                u16x8 v0 = yv[(size_t)s0 * TPN + lane];
                #pragma unroll
                for (int j = 0; j < 8; ++j)
                    a[j] = fmaf(bf2f((unsigned short)v0[j]), w0, a[j]);
            }
        }
    }
#undef EDGE_FMA
#undef SELW

    #pragma unroll
    for (int m = TPN; m < 64; m <<= 1) {
        #pragma unroll
        for (int j = 0; j < 8; ++j) a[j] += __shfl_xor(a[j], m, 64);
    }
    if (g != 0) return;

    const float inv = rsqrtf((float)(dg < 1 ? 1 : dg));
    if (FINAL) {
        float* out = (float*)outp;
        const int c = lane * 8;
        #pragma unroll
        for (int j = 0; j < 8; ++j) {
            if (c + j < 47) out[(size_t)n * 47 + c + j] = fmaf(a[j], inv, b[c + j]);
        }
    } else {
        unsigned short* out = (unsigned short*)outp;
        const float* bp = &b[lane * 8];
        u16x8 o;
        #pragma unroll
        for (int j = 0; j < 8; ++j)
            o[j] = f2bf(fmaxf(fmaf(a[j], inv, bp[j]), 0.f));
        *(u16x8*)&out[(size_t)n * PC + lane * 8] = o;
    }
}

extern "C" void kernel_launch(void* const* d_in, const int* in_sizes, int n_in,
                              void* d_out, int out_size, void* d_ws, size_t ws_size,
                              hipStream_t stream) {
    const float* x   = (const float*)d_in[0];
    const int*   src = (const int*)d_in[1];
    const int*   dst = (const int*)d_in[2];
    const float* w   = (const float*)d_in[3];
    const float* W0  = (const float*)d_in[4];
    const float* b0  = (const float*)d_in[5];
    const float* W1  = (const float*)d_in[6];
    const float* b1  = (const float*)d_in[7];
    const float* W2  = (const float*)d_in[8];
    const float* b2  = (const float*)d_in[9];

    const int N = in_sizes[0] / 128;
    const int E = in_sizes[1];

    char* p = (char*)d_ws;
    unsigned short* xh = (unsigned short*)p; p += (size_t)N * 128 * sizeof(unsigned short);
    unsigned short* y  = (unsigned short*)p; p += (size_t)N * 128 * sizeof(unsigned short);
    float4* swb    = (float4*)p; p += (size_t)N * CAP * sizeof(float4);
    int2*   spill  = (int2*)p;   p += (size_t)E * sizeof(int2);
    unsigned short* Wp = (unsigned short*)p; p += (size_t)(16384 * 2 + 8192) * sizeof(unsigned short);
    int*   dego    = (int*)p;    p += (size_t)N * sizeof(int);
    int*   cursor  = (int*)p;    p += (size_t)N * sizeof(int);   // becomes in-degree
    int*   spill_cnt = (int*)p;  p += 4 * sizeof(int);

    unsigned short* Wp1 = Wp + 16384;
    unsigned short* Wp2 = Wp + 32768;

    // ---- init: pack weights + zero counters (one dispatch) ----
    init_pack<<<160, 256, 0, stream>>>(W0, W1, W2, Wp, dego, 2 * N + 4);

    // ---- mega: graph build + layer-0 GEMM ----
    const int gemm_blocks = (N + 63) / 64;
    const int fill_blocks = (E + 255) / 256;
    int grid = 3 * gemm_blocks;
    if (grid - grid / 3 < fill_blocks) grid = (3 * fill_blocks + 1) / 2 + 2;
    mega_fill_gemm0<<<grid, 256, 0, stream>>>(
        src, dst, w, E, dego, cursor, swb, spill_cnt, spill,
        x, Wp, y, N, gemm_blocks);

    const int gather_blocks = (N + 3) / 4;

    // ---- layer 0 gather: y -> xh ----
    gather_w<128, 0, false><<<gather_blocks, 256, 0, stream>>>(
        y, swb, cursor, dego, spill_cnt, spill, src, w, b0, xh, N);

    // ---- layer 1 ----
    gemm_direct<128><<<gemm_blocks, 256, 0, stream>>>(xh, Wp1, y, N);
    gather_w<128, 1, false><<<gather_blocks, 256, 0, stream>>>(
        y, swb, cursor, dego, spill_cnt, spill, src, w + E, b1, xh, N);

    // ---- layer 2 ----
    gemm_direct<64><<<gemm_blocks, 256, 0, stream>>>(xh, Wp2, y, N);
    gather_w<64, 2, true><<<gather_blocks, 256, 0, stream>>>(
        y, swb, cursor, dego, spill_cnt, spill, src, w + 2 * (size_t)E, b2,
        d_out, N);
}

// Round 16
// 252.532 us; speedup vs baseline: 3.9771x; 1.0481x over previous
//
#include <hip/hip_runtime.h>

// ---------------------------------------------------------------------------
// 3-layer GCN (DGL GraphConv, norm='both') on N=100k nodes, E=800k edges.
// Round 16 = round 9 exactly (best known: 255.0us), plus the one clean
// residual improvement: init fusion (pack W + zero counters in a single
// dispatch, replacing memset + pack_all). NT stores NOT used (r12: fill -17us
// but gather0 +25us net loss). ushort8 gathers NOT used (r15: wash).
// Per layer: y = bf16(h @ W) ; h' = bf16(relu(sum_e y[s]*w*invo[s] *invi + b))
// ---------------------------------------------------------------------------

typedef short s16x8 __attribute__((ext_vector_type(8)));
typedef float f32x4 __attribute__((ext_vector_type(4)));

static constexpr int CAP = 24;   // bucket slots per node (P(deg>24)~1e-6)

__device__ __forceinline__ unsigned short f2bf(float f) {
    unsigned int u = __float_as_uint(f);
    u += 0x7FFFu + ((u >> 16) & 1u);   // round-to-nearest-even
    return (unsigned short)(u >> 16);
}
__device__ __forceinline__ float bf2f(unsigned short v) {
    return __uint_as_float((unsigned int)v << 16);
}

// ---- init: pack all three weight matrices into MFMA fragment order AND
//      zero the counter arrays (dego, cursor, spill_cnt) in one dispatch ----
// Fragment mapping (same for A and B, cancels HW k-order):
//   k = kk*32 + (lane>>4)*8 + j ; col = ct*16 + (lane&15)
__global__ __launch_bounds__(256)
void init_pack(const float* __restrict__ W0, const float* __restrict__ W1,
               const float* __restrict__ W2, unsigned short* __restrict__ Wp,
               int* __restrict__ zbase, int nz) {
    int idx = blockIdx.x * 256 + threadIdx.x;
    if (idx < 32768) {                       // W0 / W1, PC=128, dact=128
        const float* W = (idx < 16384) ? W0 : W1;
        unsigned short* D = Wp + ((idx < 16384) ? 0 : 16384);
        int i = idx & 16383;
        int k = i >> 7, col = i & 127;
        float v = W[k * 128 + col];
        int kk = k >> 5, kr = k & 31;
        int lane = ((kr >> 3) << 4) | (col & 15);
        int ct = col >> 4, j = kr & 7;
        D[(((kk * 8) + ct) * 64 + lane) * 8 + j] = f2bf(v);
    } else if (idx < 40960) {                // W2, PC=64, dact=47
        int i = idx - 32768;
        int k = i >> 6, col = i & 63;
        float v = (col < 47) ? W2[k * 47 + col] : 0.0f;
        int kk = k >> 5, kr = k & 31;
        int lane = ((kr >> 3) << 4) | (col & 15);
        int ct = col >> 4, j = kr & 7;
        (Wp + 32768)[(((kk * 4) + ct) * 64 + lane) * 8 + j] = f2bf(v);
    }
    for (int i = idx; i < nz; i += gridDim.x * 256) zbase[i] = 0;
}

// ---------------------------------------------------------------------------
// Mega-kernel: graph build + layer-0 GEMM in one dispatch.
// blockIdx % 3 == 2 -> gemm0 block; else fill block.
// ---------------------------------------------------------------------------
__global__ __launch_bounds__(256)
void mega_fill_gemm0(const int* __restrict__ src, const int* __restrict__ dst,
                     const float* __restrict__ w, int E,
                     int* __restrict__ dego, int* __restrict__ cursor,
                     float4* __restrict__ swb,
                     int* __restrict__ spill_cnt, int2* __restrict__ spill,
                     const float* __restrict__ x,
                     const unsigned short* __restrict__ Wp0,
                     unsigned short* __restrict__ y, int N, int gemm_blocks) {
    const int b = blockIdx.x;
    if (b % 3 == 2) {
        // ---- gemm0: y[N][128] = bf16( bf16(x) @ Wp0 ) ----
        const int gb = b / 3;
        if (gb >= gemm_blocks) return;
        const int lane = threadIdx.x & 63;
        const int wid  = threadIdx.x >> 6;
        const int row0 = gb * 64 + wid * 16;
        const int kgrp = lane >> 4;
        const int c    = lane & 15;
        int ar = row0 + c;
        if (ar > N - 1) ar = N - 1;
        const float* xrow = &x[(size_t)ar * 128];

        f32x4 acc[8];
        #pragma unroll
        for (int ct = 0; ct < 8; ++ct) acc[ct] = {0.f, 0.f, 0.f, 0.f};

        #pragma unroll
        for (int kk = 0; kk < 4; ++kk) {
            float4 u0 = *(const float4*)&xrow[kk * 32 + kgrp * 8];
            float4 u1 = *(const float4*)&xrow[kk * 32 + kgrp * 8 + 4];
            s16x8 af;
            af[0] = (short)f2bf(u0.x); af[1] = (short)f2bf(u0.y);
            af[2] = (short)f2bf(u0.z); af[3] = (short)f2bf(u0.w);
            af[4] = (short)f2bf(u1.x); af[5] = (short)f2bf(u1.y);
            af[6] = (short)f2bf(u1.z); af[7] = (short)f2bf(u1.w);
            #pragma unroll
            for (int ct = 0; ct < 8; ++ct) {
                s16x8 bf = *(const s16x8*)&Wp0[((size_t)(kk * 8 + ct) * 64 + lane) * 8];
                acc[ct] = __builtin_amdgcn_mfma_f32_16x16x32_bf16(af, bf, acc[ct], 0, 0, 0);
            }
        }
        #pragma unroll
        for (int ct = 0; ct < 8; ++ct) {
            #pragma unroll
            for (int i = 0; i < 4; ++i) {
                int row = row0 + kgrp * 4 + i;
                if (row < N) y[(size_t)row * 128 + ct * 16 + c] = f2bf(acc[ct][i]);
            }
        }
    } else {
        // ---- fill: one edge per thread ----
        const int fb = b - b / 3;            // sequential index over non-gemm blocks
        int e = fb * 256 + (int)threadIdx.x;
        if (e >= E) return;
        int s = src[e];
        int d = dst[e];
        atomicAdd(&dego[s], 1);
        int pos = atomicAdd(&cursor[d], 1);
        if (pos < CAP) {
            swb[(size_t)d * CAP + pos] =
                make_float4(__int_as_float(s), w[e], w[E + e], w[2 * (size_t)E + e]);
        } else {
            int sp = atomicAdd(spill_cnt, 1);
            spill[sp] = make_int2(d, e);
        }
    }
}

// ---------------------------------------------------------------------------
// LDS-free MFMA GEMM (layers 1,2): y[N][PC](bf16) = bf16( h[N][128](bf16) @ Wp )
// Block = 4 waves = 64 rows; wave computes 16 rows x PC cols; K=128 in 4 steps.
// C/D layout: col = ct*16 + (lane&15), row = (lane>>4)*4 + i.
// ---------------------------------------------------------------------------
template<int PC>
__global__ __launch_bounds__(256)
void gemm_direct(const unsigned short* __restrict__ h,
                 const unsigned short* __restrict__ Wp,
                 unsigned short* __restrict__ y, int N) {
    constexpr int CT = PC / 16;
    const int lane = threadIdx.x & 63;
    const int wid  = threadIdx.x >> 6;
    const int row0 = blockIdx.x * 64 + wid * 16;
    const int kgrp = lane >> 4;
    const int c    = lane & 15;

    int ar = row0 + c;
    if (ar > N - 1) ar = N - 1;
    const unsigned short* hrow = &h[(size_t)ar * 128 + kgrp * 8];

    f32x4 acc[CT];
    #pragma unroll
    for (int ct = 0; ct < CT; ++ct) acc[ct] = {0.f, 0.f, 0.f, 0.f};

    #pragma unroll
    for (int kk = 0; kk < 4; ++kk) {
        s16x8 af = *(const s16x8*)&hrow[kk * 32];
        #pragma unroll
        for (int ct = 0; ct < CT; ++ct) {
            s16x8 bf = *(const s16x8*)&Wp[((size_t)(kk * CT + ct) * 64 + lane) * 8];
            acc[ct] = __builtin_amdgcn_mfma_f32_16x16x32_bf16(af, bf, acc[ct], 0, 0, 0);
        }
    }

    #pragma unroll
    for (int ct = 0; ct < CT; ++ct) {
        #pragma unroll
        for (int i = 0; i < 4; ++i) {
            int row = row0 + kgrp * 4 + i;
            if (row < N) y[(size_t)row * PC + ct * 16 + c] = f2bf(acc[ct][i]);
        }
    }
}

// ---------------------------------------------------------------------------
// Wave-per-node gather + fused finalize (r9 form, ushort4 lanes).
// TPN = PC/4 lanes cover one row; EPG = 64/TPN edge groups on interleaved
// slots; 4/2/1-deep unrolled independent loads; shfl_xor combine.
// edge weight = w * rsqrt(max(outdeg[src],1)); invi = rsqrt(max(indeg,1)).
// ---------------------------------------------------------------------------
template<int PC, int WSEL, bool FINAL>
__global__ __launch_bounds__(256)
void gather_w(const unsigned short* __restrict__ yb, const float4* __restrict__ swb,
              const int* __restrict__ degi, const int* __restrict__ dego,
              const int* __restrict__ spill_cnt, const int2* __restrict__ spill,
              const int* __restrict__ src, const float* __restrict__ wl,
              const float* __restrict__ b, void* __restrict__ outp, int N) {
    constexpr int TPN = PC / 4;
    constexpr int EPG = 64 / TPN;
    const int n = blockIdx.x * 4 + (threadIdx.x >> 6);
    if (n >= N) return;
    const int t    = threadIdx.x & 63;
    const int lane = t & (TPN - 1);
    const int g    = t / TPN;

    const ushort4* yv = (const ushort4*)yb;
    const float4* rec = swb + (size_t)n * CAP;
    const int dg  = degi[n];
    const int cnt = dg < CAP ? dg : CAP;

    float a0 = 0.f, a1 = 0.f, a2 = 0.f, a3 = 0.f;
    int p = g;

#define SELW(m) ((WSEL == 0) ? (m).y : (WSEL == 1) ? (m).z : (m).w)
#define EDGE_FMA(m, v) do {                                                   \
        int _s = __float_as_int((m).x);                                       \
        int _d = dego[_s]; if (_d < 1) _d = 1;                                \
        float _w = SELW(m) * rsqrtf((float)_d);                               \
        a0 = fmaf(bf2f((v).x), _w, a0);                                       \
        a1 = fmaf(bf2f((v).y), _w, a1);                                       \
        a2 = fmaf(bf2f((v).z), _w, a2);                                       \
        a3 = fmaf(bf2f((v).w), _w, a3);                                       \
    } while (0)

    for (; p + 3 * EPG < cnt; p += 4 * EPG) {
        float4 m0 = rec[p];
        float4 m1 = rec[p + EPG];
        float4 m2 = rec[p + 2 * EPG];
        float4 m3 = rec[p + 3 * EPG];
        ushort4 v0 = yv[(size_t)__float_as_int(m0.x) * TPN + lane];
        ushort4 v1 = yv[(size_t)__float_as_int(m1.x) * TPN + lane];
        ushort4 v2 = yv[(size_t)__float_as_int(m2.x) * TPN + lane];
        ushort4 v3 = yv[(size_t)__float_as_int(m3.x) * TPN + lane];
        EDGE_FMA(m0, v0); EDGE_FMA(m1, v1); EDGE_FMA(m2, v2); EDGE_FMA(m3, v3);
    }
    for (; p + EPG < cnt; p += 2 * EPG) {
        float4 m0 = rec[p];
        float4 m1 = rec[p + EPG];
        ushort4 v0 = yv[(size_t)__float_as_int(m0.x) * TPN + lane];
        ushort4 v1 = yv[(size_t)__float_as_int(m1.x) * TPN + lane];
        EDGE_FMA(m0, v0); EDGE_FMA(m1, v1);
    }
    if (p < cnt) {
        float4 m0 = rec[p];
        ushort4 v0 = yv[(size_t)__float_as_int(m0.x) * TPN + lane];
        EDGE_FMA(m0, v0);
    }
    if (dg > CAP && g == 0) {            // exact-overflow path (empty in practice)
        int sc = *spill_cnt;
        for (int i = 0; i < sc; ++i) {
            int2 sp = spill[i];
            if (sp.x == n) {
                int e = sp.y;
                int s0 = src[e];
                int d0 = dego[s0]; if (d0 < 1) d0 = 1;
                float w0 = wl[e] * rsqrtf((float)d0);
                ushort4 v0 = yv[(size_t)s0 * TPN + lane];
                a0 = fmaf(bf2f(v0.x), w0, a0);
                a1 = fmaf(bf2f(v0.y), w0, a1);
                a2 = fmaf(bf2f(v0.z), w0, a2);
                a3 = fmaf(bf2f(v0.w), w0, a3);
            }
        }
    }
#undef EDGE_FMA
#undef SELW

    #pragma unroll
    for (int m = TPN; m < 64; m <<= 1) {
        a0 += __shfl_xor(a0, m, 64);
        a1 += __shfl_xor(a1, m, 64);
        a2 += __shfl_xor(a2, m, 64);
        a3 += __shfl_xor(a3, m, 64);
    }
    if (g != 0) return;

    const float inv = rsqrtf((float)(dg < 1 ? 1 : dg));
    if (FINAL) {
        float* out = (float*)outp;
        const int c = lane * 4;
        float aa[4] = {a0, a1, a2, a3};
        #pragma unroll
        for (int j = 0; j < 4; ++j) {
            if (c + j < 47) out[(size_t)n * 47 + c + j] = fmaf(aa[j], inv, b[c + j]);
        }
    } else {
        unsigned short* out = (unsigned short*)outp;
        float4 bb = *(const float4*)&b[lane * 4];
        float4 v;
        v.x = fmaxf(fmaf(a0, inv, bb.x), 0.f);
        v.y = fmaxf(fmaf(a1, inv, bb.y), 0.f);
        v.z = fmaxf(fmaf(a2, inv, bb.z), 0.f);
        v.w = fmaxf(fmaf(a3, inv, bb.w), 0.f);
        ushort4 o;
        o.x = f2bf(v.x); o.y = f2bf(v.y); o.z = f2bf(v.z); o.w = f2bf(v.w);
        *(ushort4*)&out[(size_t)n * PC + lane * 4] = o;
    }
}

extern "C" void kernel_launch(void* const* d_in, const int* in_sizes, int n_in,
                              void* d_out, int out_size, void* d_ws, size_t ws_size,
                              hipStream_t stream) {
    const float* x   = (const float*)d_in[0];
    const int*   src = (const int*)d_in[1];
    const int*   dst = (const int*)d_in[2];
    const float* w   = (const float*)d_in[3];
    const float* W0  = (const float*)d_in[4];
    const float* b0  = (const float*)d_in[5];
    const float* W1  = (const float*)d_in[6];
    const float* b1  = (const float*)d_in[7];
    const float* W2  = (const float*)d_in[8];
    const float* b2  = (const float*)d_in[9];

    const int N = in_sizes[0] / 128;
    const int E = in_sizes[1];

    char* p = (char*)d_ws;
    unsigned short* xh = (unsigned short*)p; p += (size_t)N * 128 * sizeof(unsigned short);
    unsigned short* y  = (unsigned short*)p; p += (size_t)N * 128 * sizeof(unsigned short);
    float4* swb    = (float4*)p; p += (size_t)N * CAP * sizeof(float4);
    int2*   spill  = (int2*)p;   p += (size_t)E * sizeof(int2);
    unsigned short* Wp = (unsigned short*)p; p += (size_t)(16384 * 2 + 8192) * sizeof(unsigned short);
    int*   dego    = (int*)p;    p += (size_t)N * sizeof(int);
    int*   cursor  = (int*)p;    p += (size_t)N * sizeof(int);   // becomes in-degree
    int*   spill_cnt = (int*)p;  p += 4 * sizeof(int);

    unsigned short* Wp1 = Wp + 16384;
    unsigned short* Wp2 = Wp + 32768;

    // ---- init: pack weights + zero counters (one dispatch) ----
    init_pack<<<160, 256, 0, stream>>>(W0, W1, W2, Wp, dego, 2 * N + 4);

    // ---- mega: graph build + layer-0 GEMM ----
    const int gemm_blocks = (N + 63) / 64;
    const int fill_blocks = (E + 255) / 256;
    int grid = 3 * gemm_blocks;
    if (grid - grid / 3 < fill_blocks) grid = (3 * fill_blocks + 1) / 2 + 2;
    mega_fill_gemm0<<<grid, 256, 0, stream>>>(
        src, dst, w, E, dego, cursor, swb, spill_cnt, spill,
        x, Wp, y, N, gemm_blocks);

    const int gather_blocks = (N + 3) / 4;

    // ---- layer 0 gather: y -> xh ----
    gather_w<128, 0, false><<<gather_blocks, 256, 0, stream>>>(
        y, swb, cursor, dego, spill_cnt, spill, src, w, b0, xh, N);

    // ---- layer 1 ----
    gemm_direct<128><<<gemm_blocks, 256, 0, stream>>>(xh, Wp1, y, N);
    gather_w<128, 1, false><<<gather_blocks, 256, 0, stream>>>(
        y, swb, cursor, dego, spill_cnt, spill, src, w + E, b1, xh, N);

    // ---- layer 2 ----
    gemm_direct<64><<<gemm_blocks, 256, 0, stream>>>(xh, Wp2, y, N);
    gather_w<64, 2, true><<<gather_blocks, 256, 0, stream>>>(
        y, swb, cursor, dego, spill_cnt, spill, src, w + 2 * (size_t)E, b2,
        d_out, N);
}